// Round 7
// baseline (204.266 us; speedup 1.0000x reference)
//
#include <hip/hip_runtime.h>
#include <math.h>

#define N_  32
#define T_  8192
#define D_  64
#define K_  64
#define CHUNKS 24                      // 768 blocks = exactly 3/CU, one round
#define TB 64                          // tokens per batch
#define STATS_PER_N (K_ + 2 * K_ * D_) // 8256
#define XSTR 72                        // f16 stride for Xs/Pt rows

typedef _Float16 half_t;
typedef __attribute__((ext_vector_type(8)))  _Float16 v8h;
typedef __attribute__((ext_vector_type(4)))  float    v4f;
typedef __attribute__((ext_vector_type(16))) float    v16f;

// lgkm-only barrier (producer prefetches stay in flight). No sched_barrier
// pinning (R6 showed it regresses); the asm memory clobber orders LDS ops.
#define BAR_LDS() do {                                                  \
    asm volatile("s_waitcnt lgkmcnt(0)" ::: "memory");                  \
    __builtin_amdgcn_s_barrier();                                       \
} while (0)

// ---------------------------------------------------------------------------
// prep (grid 9): blocks 0..7 pack WH (f16 MFMA A-frag order);
// block 8: Ap[k] = 2 log w - 0.5*sum_d(log c + mu^2/c), and zero ssq[32].
// ---------------------------------------------------------------------------
__global__ void prep_kernel(const float* __restrict__ w, const float* __restrict__ mu,
                            const float* __restrict__ cv, float* __restrict__ Ap,
                            half_t* __restrict__ WH, float* __restrict__ ssq) {
    if (blockIdx.x < 8) {
#pragma unroll
        for (int i = 0; i < 4; ++i) {
            const int e = blockIdx.x * 1024 + i * 256 + threadIdx.x;  // 0..8191
            const int j = e & 7, l = (e >> 3) & 63, fs = e >> 9;
            const int tile = fs >> 2, s = fs & 3;
            const int kc = 16 * tile + (l & 15);
            const int f  = 32 * s + 8 * (l >> 4) + j;
            float val;
            if (f < 64) val = mu[kc * 64 + f] / cv[kc * 64 + f];
            else        val = -0.5f / cv[kc * 64 + (f - 64)];
            WH[e] = (half_t)val;
        }
    } else {
        if (threadIdx.x < 32) ssq[threadIdx.x] = 0.f;
        if (threadIdx.x < K_) {
            const int k = threadIdx.x;
            float acc = 0.f;
            for (int d = 0; d < D_; ++d) {
                const int idx = k * D_ + d;
                const float c = cv[idx], m = mu[idx];
                acc += logf(c) + m * m / c;
            }
            Ap[k] = 2.f * logf(w[k]) - 0.5f * acc;
        }
    }
}

// ---------------------------------------------------------------------------
// main: grid (24, 32) = 768 blocks, block 256 (4 waves), 3 blocks/CU.
// R7: PRODUCER/CONSUMER wave specialization. Waves 0-1 (producers) each own
// 32 tokens/batch: x load -> f16 frags -> Phase-A MFMA -> softmax -> Pt/Xs
// into LDS buf (b&1). Waves 2-3 (consumers) each own one sig (x / x^2) and
// the FULL k x d accumulation from buf ((b-1)&1) -- pure LDS+MFMA, squaring
// x on the fly for sig=1 (validated R5). Producer(b+1) overlaps consumer(b);
// ONE lgkm-only barrier per period; cnt+1 periods vs old 2*cnt barriers with
// full serialization. LDS 2*(Xs+Pt)+s0sh = 37.4 KB -> 3 blocks/CU.
// ---------------------------------------------------------------------------
__launch_bounds__(256, 3)
__global__ void main_kernel(const float* __restrict__ x, const float* __restrict__ Ap,
                            const half_t* __restrict__ WH, float* __restrict__ outbuf,
                            int mode) {
    __shared__ half_t Xs[2][TB][XSTR];   // 18.0 KB
    __shared__ half_t Pt[2][K_][XSTR];   // 18.0 KB
    __shared__ float  s0sh[2][64];       // 0.5 KB

    const int tid  = threadIdx.x;
    const int lane = tid & 63;
    const int wv   = tid >> 6;
    const int chunk = blockIdx.x;
    const int n     = blockIdx.y;
    const int q    = lane >> 4;
    const int c0   = lane & 15;

    // batch range (balanced 5/6 as R3)
    const int r3   = (3 - (n % 3)) % 3;
    const int hcnt = (chunk + 2 - r3) / 3;
    const int boff = 5 * chunk + hcnt;
    const int cnt  = 5 + ((chunk % 3) == r3 ? 1 : 0);

    const size_t xbase = ((size_t)n * T_ + (size_t)boff * TB) * (size_t)D_;
    const bool producer = (wv < 2);
    const int  sig = wv - 2;             // consumers only

    // ---- producer state ----
    v8h  Wf[16];
    v4f  apv4[4];
    float S0loc[16];
    float4 RA[4], RB[4];
    const float* xrowA = nullptr;
    const float* xrowB = nullptr;

    // ---- consumer state ----
    v16f accB[2][2];

    if (producer) {
#pragma unroll
        for (int t = 0; t < 4; ++t)
#pragma unroll
            for (int s = 0; s < 4; ++s)
                Wf[t * 4 + s] = *(const v8h*)(WH + (size_t)((t * 4 + s) * 64 + lane) * 8);
#pragma unroll
        for (int t = 0; t < 4; ++t) apv4[t] = *(const v4f*)(Ap + 16 * t + 4 * q);
#pragma unroll
        for (int j = 0; j < 16; ++j) S0loc[j] = 0.f;
        xrowA = x + xbase + (size_t)(16 * (2 * wv)     + c0) * 64 + 8 * q;
        xrowB = x + xbase + (size_t)(16 * (2 * wv + 1) + c0) * 64 + 8 * q;
        RA[0] = *(const float4*)(xrowA);      RA[1] = *(const float4*)(xrowA + 4);
        RA[2] = *(const float4*)(xrowA + 32); RA[3] = *(const float4*)(xrowA + 36);
        RB[0] = *(const float4*)(xrowB);      RB[1] = *(const float4*)(xrowB + 4);
        RB[2] = *(const float4*)(xrowB + 32); RB[3] = *(const float4*)(xrowB + 36);
    } else {
#pragma unroll
        for (int a = 0; a < 2; ++a)
#pragma unroll
            for (int bb = 0; bb < 2; ++bb)
#pragma unroll
                for (int r = 0; r < 16; ++r) accB[a][bb][r] = 0.f;
    }

#pragma unroll 1
    for (int b = 0; b <= cnt; ++b) {
        if (producer && b < cnt) {
            const int buf = b & 1;
#pragma unroll
            for (int g = 0; g < 2; ++g) {
                float4* Rg = g ? RB : RA;
                const int tok = 16 * (2 * wv + g) + c0;
                // convert -> frags + stage Xs
                v8h xh0, xh1, qh0, qh1;
                {
                    const float4 a = Rg[0], bq = Rg[1], c = Rg[2], d = Rg[3];
                    xh0[0] = (half_t)a.x;  xh0[1] = (half_t)a.y;  xh0[2] = (half_t)a.z;  xh0[3] = (half_t)a.w;
                    xh0[4] = (half_t)bq.x; xh0[5] = (half_t)bq.y; xh0[6] = (half_t)bq.z; xh0[7] = (half_t)bq.w;
                    xh1[0] = (half_t)c.x;  xh1[1] = (half_t)c.y;  xh1[2] = (half_t)c.z;  xh1[3] = (half_t)c.w;
                    xh1[4] = (half_t)d.x;  xh1[5] = (half_t)d.y;  xh1[6] = (half_t)d.z;  xh1[7] = (half_t)d.w;
                    qh0 = xh0 * xh0;
                    qh1 = xh1 * xh1;
                    *(v8h*)&Xs[buf][tok][8 * q]      = xh0;
                    *(v8h*)&Xs[buf][tok][32 + 8 * q] = xh1;
                }
                // prefetch next batch for this group (in flight across barrier)
                if (b + 1 < cnt) {
                    const float* xr = (g ? xrowB : xrowA) + (size_t)(b + 1) * TB * D_;
                    Rg[0] = *(const float4*)(xr);
                    Rg[1] = *(const float4*)(xr + 4);
                    Rg[2] = *(const float4*)(xr + 32);
                    Rg[3] = *(const float4*)(xr + 36);
                }
                // Phase A MFMA (C-init = Ap bias)
                v4f acc[4];
#pragma unroll
                for (int t = 0; t < 4; ++t) acc[t] = apv4[t];
#pragma unroll
                for (int t = 0; t < 4; ++t) {
                    acc[t] = __builtin_amdgcn_mfma_f32_16x16x32_f16(Wf[t * 4 + 0], xh0, acc[t], 0, 0, 0);
                    acc[t] = __builtin_amdgcn_mfma_f32_16x16x32_f16(Wf[t * 4 + 1], xh1, acc[t], 0, 0, 0);
                    acc[t] = __builtin_amdgcn_mfma_f32_16x16x32_f16(Wf[t * 4 + 2], qh0, acc[t], 0, 0, 0);
                    acc[t] = __builtin_amdgcn_mfma_f32_16x16x32_f16(Wf[t * 4 + 3], qh1, acc[t], 0, 0, 0);
                }
                // softmax over k (lane group of 4 x 16)
                float pv[16];
                float m = -1e30f;
#pragma unroll
                for (int t = 0; t < 4; ++t)
#pragma unroll
                    for (int r = 0; r < 4; ++r) {
                        pv[t * 4 + r] = acc[t][r];
                        m = fmaxf(m, acc[t][r]);
                    }
                m = fmaxf(m, __shfl_xor(m, 16, 64));
                m = fmaxf(m, __shfl_xor(m, 32, 64));
                float ssum = 0.f;
#pragma unroll
                for (int j = 0; j < 16; ++j) { pv[j] = __expf(pv[j] - m); ssum += pv[j]; }
                ssum += __shfl_xor(ssum, 16, 64);
                ssum += __shfl_xor(ssum, 32, 64);
                const float rs = 1.f / ssum;
#pragma unroll
                for (int j = 0; j < 16; ++j) { pv[j] *= rs; S0loc[j] += pv[j]; }
#pragma unroll
                for (int t = 0; t < 4; ++t)
#pragma unroll
                    for (int r = 0; r < 4; ++r)
                        Pt[buf][16 * t + 4 * q + r][tok] = (half_t)pv[t * 4 + r];
            }
        }
        if (!producer && b > 0) {
            const int buf = (b - 1) & 1;
            const int m = lane & 31;
            const int h = lane >> 5;
            const half_t* Arow0 = &Pt[buf][m][0];
            const half_t* Arow1 = &Pt[buf][32 + m][0];
            const half_t* Bs    = &Xs[buf][0][0];
#pragma unroll
            for (int st = 0; st < 4; ++st) {
                const int tBk = 16 * st + 8 * h;
                const v8h a0 = *(const v8h*)(Arow0 + tBk);
                const v8h a1 = *(const v8h*)(Arow1 + tBk);
#pragma unroll
                for (int dhf = 0; dhf < 2; ++dhf) {
                    const int d = 32 * dhf + m;
                    v8h bf;
#pragma unroll
                    for (int j = 0; j < 8; ++j)
                        bf[j] = Bs[(tBk + j) * XSTR + d];
                    if (sig) bf = bf * bf;   // x^2 on the fly
                    accB[0][dhf] = __builtin_amdgcn_mfma_f32_32x32x16_f16(a0, bf, accB[0][dhf], 0, 0, 0);
                    accB[1][dhf] = __builtin_amdgcn_mfma_f32_32x32x16_f16(a1, bf, accB[1][dhf], 0, 0, 0);
                }
            }
        }
        BAR_LDS();   // one barrier per period; producer prefetch not drained
    }

    // -------- flush --------
    if (producer) {
#pragma unroll
        for (int j = 0; j < 16; ++j) {
            float v = S0loc[j];
            v += __shfl_xor(v, 1, 64);
            v += __shfl_xor(v, 2, 64);
            v += __shfl_xor(v, 4, 64);
            v += __shfl_xor(v, 8, 64);
            S0loc[j] = v;
        }
        if (c0 == 0) {
#pragma unroll
            for (int t = 0; t < 4; ++t)
#pragma unroll
                for (int r = 0; r < 4; ++r)
                    s0sh[wv][16 * t + 4 * q + r] = S0loc[t * 4 + r];
        }
    }
    __syncthreads();

    if (mode == 1) {
        float* dstb = outbuf + (size_t)(n * CHUNKS + chunk) * STATS_PER_N;
        if (tid < 64)
            dstb[tid] = s0sh[0][tid] + s0sh[1][tid];
        if (!producer) {
            float* dst = dstb + 64 + sig * 4096;
#pragma unroll
            for (int mt = 0; mt < 2; ++mt)
#pragma unroll
                for (int dhf = 0; dhf < 2; ++dhf)
#pragma unroll
                    for (int r = 0; r < 16; ++r) {
                        const int kc = 32 * mt + (r & 3) + 8 * (r >> 2) + 4 * (lane >> 5);
                        const int d  = 32 * dhf + (lane & 31);
                        dst[kc * 64 + d] = accB[mt][dhf][r];
                    }
        }
    } else {
        float* sb = outbuf + (size_t)n * STATS_PER_N;
        if (tid < 64)
            atomicAdd(&sb[tid], s0sh[0][tid] + s0sh[1][tid]);
        if (!producer) {
            float* dst = sb + 64 + sig * 4096;
#pragma unroll
            for (int mt = 0; mt < 2; ++mt)
#pragma unroll
                for (int dhf = 0; dhf < 2; ++dhf)
#pragma unroll
                    for (int r = 0; r < 16; ++r) {
                        const int kc = 32 * mt + (r & 3) + 8 * (r >> 2) + 4 * (lane >> 5);
                        const int d  = 32 * dhf + (lane & 31);
                        atomicAdd(&dst[kc * 64 + d], accB[mt][dhf][r]);
                    }
        }
    }
}

// ---------------------------------------------------------------------------
// reduce_pow (grid (33, N)): R3 verbatim (measured best total).
// ---------------------------------------------------------------------------
__global__ void reduce_pow_kernel(const float* __restrict__ partials,
                                  const float* __restrict__ w, const float* __restrict__ mu,
                                  const float* __restrict__ cv,
                                  float* __restrict__ us, float* __restrict__ ssq) {
    __shared__ float red[4];
    const int e = blockIdx.x * 256 + threadIdx.x;
    const int n = blockIdx.y;
    float u = 0.f;
    if (e < STATS_PER_N) {
        const float* base = partials + (size_t)n * CHUNKS * STATS_PER_N;
        float sv = 0.f;
#pragma unroll 8
        for (int c = 0; c < CHUNKS; ++c) sv += base[(size_t)c * STATS_PER_N + e];
        float v; int oidx;
        if (e < 64) {
            const float wv = w[e];
            v = (sv - (float)T_ * wv) * rsqrtf(wv);
            oidx = e * 129;
        } else if (e < 64 + 4096) {
            const int idx = e - 64, k = idx >> 6, d = idx & 63;
            float s0v = 0.f;
#pragma unroll 8
            for (int c = 0; c < CHUNKS; ++c) s0v += base[(size_t)c * STATS_PER_N + k];
            v = (sv - mu[idx] * s0v) * rsqrtf(w[k] * cv[idx]);
            oidx = k * 129 + 1 + d;
        } else {
            const int idx = e - 4160, k = idx >> 6, d = idx & 63;
            float s0v = 0.f, s1v = 0.f;
#pragma unroll 4
            for (int c = 0; c < CHUNKS; ++c) {
                s0v += base[(size_t)c * STATS_PER_N + k];
                s1v += base[(size_t)c * STATS_PER_N + 64 + idx];
            }
            const float m_ = mu[idx], c_ = cv[idx];
            v = (sv - 2.f * m_ * s1v + (m_ * m_ - c_) * s0v) * (rsqrtf(2.f * w[k]) / c_);
            oidx = k * 129 + 65 + d;
        }
        u = (v >= 0.f) ? sqrtf(v) : -sqrtf(-v);
        us[(size_t)n * STATS_PER_N + oidx] = u;
    }
    float ss = u * u;
#pragma unroll
    for (int off = 32; off > 0; off >>= 1) ss += __shfl_xor(ss, off, 64);
    if ((threadIdx.x & 63) == 0) red[threadIdx.x >> 6] = ss;
    __syncthreads();
    if (threadIdx.x == 0)
        atomicAdd(&ssq[n], red[0] + red[1] + red[2] + red[3]);
}

// ---------------------------------------------------------------------------
// scale (grid (33, N)): out = us * rsqrt(ssq[n])
// ---------------------------------------------------------------------------
__global__ void scale_kernel(const float* __restrict__ us, const float* __restrict__ ssq,
                             float* __restrict__ out) {
    const int e = blockIdx.x * 256 + threadIdx.x;
    const int n = blockIdx.y;
    if (e < STATS_PER_N)
        out[(size_t)n * STATS_PER_N + e] = us[(size_t)n * STATS_PER_N + e] * rsqrtf(ssq[n]);
}

// ---------------------------------------------------------------------------
// fallback finalize (small-ws atomic path).
// ---------------------------------------------------------------------------
__global__ void fin_kernel(const float* __restrict__ w, const float* __restrict__ mu,
                           const float* __restrict__ cv, const float* __restrict__ stats,
                           float* __restrict__ out) {
    __shared__ float us[STATS_PER_N];
    __shared__ float red[4];
    const int n   = blockIdx.x;
    const int tid = threadIdx.x;
    const float* sb = stats + (size_t)n * STATS_PER_N;

    float ss = 0.f;
    if (tid < 64) {
        const float wv = w[tid];
        const float v = (sb[tid] - (float)T_ * wv) * rsqrtf(wv);
        const float u = (v >= 0.f) ? sqrtf(v) : -sqrtf(-v);
        us[tid * 129] = u;
        ss = fmaf(u, u, ss);
    }
#pragma unroll 1
    for (int i = 0; i < 16; ++i) {
        const int idx = i * 256 + tid;
        const int k = idx >> 6, d = idx & 63;
        const float v = (sb[64 + idx] - mu[idx] * sb[k]) * rsqrtf(w[k] * cv[idx]);
        const float u = (v >= 0.f) ? sqrtf(v) : -sqrtf(-v);
        us[k * 129 + 1 + d] = u;
        ss = fmaf(u, u, ss);
    }
#pragma unroll 1
    for (int i = 0; i < 16; ++i) {
        const int idx = i * 256 + tid;
        const int k = idx >> 6, d = idx & 63;
        const float m_ = mu[idx], c_ = cv[idx];
        const float s1v = sb[64 + idx], s2v = sb[64 + 4096 + idx];
        const float v = (s2v - 2.f * m_ * s1v + (m_ * m_ - c_) * sb[k]) *
                        (rsqrtf(2.f * w[k]) / c_);
        const float u = (v >= 0.f) ? sqrtf(v) : -sqrtf(-v);
        us[k * 129 + 65 + d] = u;
        ss = fmaf(u, u, ss);
    }
#pragma unroll
    for (int off = 32; off > 0; off >>= 1) ss += __shfl_xor(ss, off, 64);
    if ((tid & 63) == 0) red[tid >> 6] = ss;
    __syncthreads();
    const float tot = red[0] + red[1] + red[2] + red[3];
    const float rn = rsqrtf(tot);
    for (int e = tid; e < STATS_PER_N; e += 256)
        out[(size_t)n * STATS_PER_N + e] = us[e] * rn;
}

// ---------------------------------------------------------------------------
extern "C" void kernel_launch(void* const* d_in, const int* in_sizes, int n_in,
                              void* d_out, int out_size, void* d_ws, size_t ws_size,
                              hipStream_t stream) {
    const float* x  = (const float*)d_in[0];
    const float* w  = (const float*)d_in[1];
    const float* mu = (const float*)d_in[2];
    const float* cv = (const float*)d_in[3];
    float* out = (float*)d_out;

    const size_t part_elems = (size_t)CHUNKS * N_ * STATS_PER_N;   // 6.34M floats
    const size_t us_elems   = (size_t)N_ * STATS_PER_N;
    const size_t need_big = (part_elems + us_elems + 32 + K_ + (size_t)K_ * 64) * sizeof(float);

    if (ws_size >= need_big) {
        float* partials = (float*)d_ws;
        float* us  = partials + part_elems;
        float* ssq = us + us_elems;
        float* Ap  = ssq + 32;
        half_t* WH = (half_t*)(Ap + K_);

        prep_kernel<<<9, 256, 0, stream>>>(w, mu, cv, Ap, WH, ssq);
        main_kernel<<<dim3(CHUNKS, N_), 256, 0, stream>>>(x, Ap, WH, partials, 1);
        reduce_pow_kernel<<<dim3(33, N_), 256, 0, stream>>>(partials, w, mu, cv, us, ssq);
        scale_kernel<<<dim3(33, N_), 256, 0, stream>>>(us, ssq, out);
    } else {
        float* stats = (float*)d_ws;
        float* ssq = stats + us_elems;
        float* Ap  = ssq + 32;
        half_t* WH = (half_t*)(Ap + K_);

        hipMemsetAsync(stats, 0, us_elems * sizeof(float), stream);
        prep_kernel<<<9, 256, 0, stream>>>(w, mu, cv, Ap, WH, ssq);
        main_kernel<<<dim3(CHUNKS, N_), 256, 0, stream>>>(x, Ap, WH, stats, 0);
        fin_kernel<<<N_, 256, 0, stream>>>(w, mu, cv, stats, out);
    }
}

// Round 8
// 155.994 us; speedup vs baseline: 1.3095x; 1.3095x over previous
//
#include <hip/hip_runtime.h>
#include <math.h>

#define N_  32
#define T_  8192
#define D_  64
#define K_  64
#define CHUNKS 24                      // 768 blocks = exactly 3/CU, one round
#define TB 64                          // tokens per batch
#define STATS_PER_N (K_ + 2 * K_ * D_) // 8256
#define XSTR 72                        // f16 stride for Xs/Qs/Pt rows
#define STATS_TOTAL (N_ * STATS_PER_N) // 264192 floats
#define STATS_F4    (STATS_TOTAL / 4)  // 66048 float4

typedef _Float16 half_t;
typedef __attribute__((ext_vector_type(8)))  _Float16 v8h;
typedef __attribute__((ext_vector_type(4)))  float    v4f;
typedef __attribute__((ext_vector_type(16))) float    v16f;

// ---------------------------------------------------------------------------
// prep (grid 42): blocks 0..7 pack WH (f16 MFMA A-frag order);
// block 8: Ap[k] = 2 log w - 0.5*sum_d(log c + mu^2/c);
// blocks 9..41: zero the 1 MB stats buffer (replaces a hipMemsetAsync node).
// ---------------------------------------------------------------------------
__global__ void prep_kernel(const float* __restrict__ w, const float* __restrict__ mu,
                            const float* __restrict__ cv, float* __restrict__ Ap,
                            half_t* __restrict__ WH, float* __restrict__ stats) {
    if (blockIdx.x < 8) {
#pragma unroll
        for (int i = 0; i < 4; ++i) {
            const int e = blockIdx.x * 1024 + i * 256 + threadIdx.x;  // 0..8191
            const int j = e & 7, l = (e >> 3) & 63, fs = e >> 9;
            const int tile = fs >> 2, s = fs & 3;
            const int kc = 16 * tile + (l & 15);
            const int f  = 32 * s + 8 * (l >> 4) + j;
            float val;
            if (f < 64) val = mu[kc * 64 + f] / cv[kc * 64 + f];
            else        val = -0.5f / cv[kc * 64 + (f - 64)];
            WH[e] = (half_t)val;
        }
    } else if (blockIdx.x == 8) {
        if (threadIdx.x < K_) {
            const int k = threadIdx.x;
            float acc = 0.f;
            for (int d = 0; d < D_; ++d) {
                const int idx = k * D_ + d;
                const float c = cv[idx], m = mu[idx];
                acc += logf(c) + m * m / c;
            }
            Ap[k] = 2.f * logf(w[k]) - 0.5f * acc;
        }
    } else {
        // zero stats: 33 blocks x 256 threads x 8 float4 = 67584 >= 66048
        const int b = blockIdx.x - 9;
        float4 z; z.x = z.y = z.z = z.w = 0.f;
#pragma unroll
        for (int i = 0; i < 8; ++i) {
            const int idx = (b * 8 + i) * 256 + threadIdx.x;
            if (idx < STATS_F4) ((float4*)stats)[idx] = z;
        }
    }
}

// ---------------------------------------------------------------------------
// main: grid (24, 32) = 768 blocks, block 256 (4 waves).  Inner loop is the
// R3 best-measured structure VERBATIM (47.2 us): W-in-registers, f16 Xs/Qs
// staging, register x-prefetch, 28.6 KB LDS, 2 barriers/batch, balanced
// 5/6-batch chunks. R8 change is OUTSIDE the loop: always mode 0 — the
// flush atomicAdds into a 1 MB stats buffer (atomics accumulate in L2,
// contiguous 128B per wave -> coalesced; replaces 25 MB partials HBM write
// + 25 MB reduce re-read + 2 launches).
// ---------------------------------------------------------------------------
__launch_bounds__(256, 3)
__global__ void main_kernel(const float* __restrict__ x, const float* __restrict__ Ap,
                            const half_t* __restrict__ WH, float* __restrict__ outbuf,
                            int mode) {
    __shared__ half_t Xs[TB][XSTR];   // 9.0 KB
    __shared__ half_t Qs[TB][XSTR];   // 9.0 KB
    __shared__ half_t Pt[K_][XSTR];   // 9.0 KB (transposed p: row=kc, col=token)
    __shared__ float  s0sh[4][64];    // 1.0 KB

    const int tid  = threadIdx.x;
    const int lane = tid & 63;
    const int wv   = tid >> 6;
    const int chunk = blockIdx.x;
    const int n     = blockIdx.y;
    const int q     = lane >> 4;
    const int c0    = lane & 15;
    const int tok   = 16 * wv + c0;   // this lane's token within the batch

    // batch range for this (n, chunk): heavy chunks (6 batches) where
    // (chunk % 3) == r, others 5; off = 5*chunk + #heavies before chunk.
    const int r3   = (3 - (n % 3)) % 3;
    const int hcnt = (chunk + 2 - r3) / 3;          // heavies in [0, chunk)
    const int boff = 5 * chunk + hcnt;              // first batch index
    const int cnt  = 5 + ((chunk % 3) == r3 ? 1 : 0);

    // resident weight A-frags
    v8h Wf[16];
#pragma unroll
    for (int t = 0; t < 4; ++t)
#pragma unroll
        for (int s = 0; s < 4; ++s)
            Wf[t * 4 + s] = *(const v8h*)(WH + (size_t)((t * 4 + s) * 64 + lane) * 8);

    float apv[16];
#pragma unroll
    for (int t = 0; t < 4; ++t)
#pragma unroll
        for (int r = 0; r < 4; ++r) apv[t * 4 + r] = Ap[16 * t + 4 * q + r];

    float S0loc[16];
#pragma unroll
    for (int j = 0; j < 16; ++j) S0loc[j] = 0.f;

    const int sig = wv >> 1;
    const int dh  = wv & 1;
    v16f accB[2];
#pragma unroll
    for (int m = 0; m < 2; ++m)
#pragma unroll
        for (int r = 0; r < 16; ++r) accB[m][r] = 0.f;

    const size_t xbase = ((size_t)n * T_ + (size_t)boff * TB) * (size_t)D_;
    // Phase-A load geometry: lane reads token `tok`, d in [8q,8q+8) and [32+8q,+8)
    const float* xrow0 = x + xbase + tok * 64 + 8 * q;

    // preload batch 0
    float4 R[4];
    R[0] = *(const float4*)(xrow0);
    R[1] = *(const float4*)(xrow0 + 4);
    R[2] = *(const float4*)(xrow0 + 32);
    R[3] = *(const float4*)(xrow0 + 36);

#pragma unroll 1
    for (int batch = 0; batch < cnt; ++batch) {
        // ---- convert current R -> frags (registers), stage to LDS for Phase B ----
        v8h xh0, xh1, qh0, qh1;
        {
            const float4 a = R[0], b = R[1], c = R[2], d = R[3];
            xh0[0] = (half_t)a.x; xh0[1] = (half_t)a.y; xh0[2] = (half_t)a.z; xh0[3] = (half_t)a.w;
            xh0[4] = (half_t)b.x; xh0[5] = (half_t)b.y; xh0[6] = (half_t)b.z; xh0[7] = (half_t)b.w;
            xh1[0] = (half_t)c.x; xh1[1] = (half_t)c.y; xh1[2] = (half_t)c.z; xh1[3] = (half_t)c.w;
            xh1[4] = (half_t)d.x; xh1[5] = (half_t)d.y; xh1[6] = (half_t)d.z; xh1[7] = (half_t)d.w;
            qh0[0] = (half_t)(a.x * a.x); qh0[1] = (half_t)(a.y * a.y);
            qh0[2] = (half_t)(a.z * a.z); qh0[3] = (half_t)(a.w * a.w);
            qh0[4] = (half_t)(b.x * b.x); qh0[5] = (half_t)(b.y * b.y);
            qh0[6] = (half_t)(b.z * b.z); qh0[7] = (half_t)(b.w * b.w);
            qh1[0] = (half_t)(c.x * c.x); qh1[1] = (half_t)(c.y * c.y);
            qh1[2] = (half_t)(c.z * c.z); qh1[3] = (half_t)(c.w * c.w);
            qh1[4] = (half_t)(d.x * d.x); qh1[5] = (half_t)(d.y * d.y);
            qh1[6] = (half_t)(d.z * d.z); qh1[7] = (half_t)(d.w * d.w);
            *(v8h*)&Xs[tok][8 * q]      = xh0;
            *(v8h*)&Xs[tok][32 + 8 * q] = xh1;
            *(v8h*)&Qs[tok][8 * q]      = qh0;
            *(v8h*)&Qs[tok][32 + 8 * q] = qh1;
        }

        // ---- prefetch next batch (latency hidden under A-MFMA + softmax + B) ----
        if (batch + 1 < cnt) {
            const float* xr = xrow0 + (size_t)(batch + 1) * TB * D_;
            R[0] = *(const float4*)(xr);
            R[1] = *(const float4*)(xr + 4);
            R[2] = *(const float4*)(xr + 32);
            R[3] = *(const float4*)(xr + 36);
        }

        // ---------------- Phase A (register frags only) ----------------
        {
            v4f acc[4];
#pragma unroll
            for (int t = 0; t < 4; ++t) acc[t] = (v4f)(0.f);
#pragma unroll
            for (int t = 0; t < 4; ++t) {
                acc[t] = __builtin_amdgcn_mfma_f32_16x16x32_f16(Wf[t * 4 + 0], xh0, acc[t], 0, 0, 0);
                acc[t] = __builtin_amdgcn_mfma_f32_16x16x32_f16(Wf[t * 4 + 1], xh1, acc[t], 0, 0, 0);
                acc[t] = __builtin_amdgcn_mfma_f32_16x16x32_f16(Wf[t * 4 + 2], qh0, acc[t], 0, 0, 0);
                acc[t] = __builtin_amdgcn_mfma_f32_16x16x32_f16(Wf[t * 4 + 3], qh1, acc[t], 0, 0, 0);
            }
            float pv[16];
            float m = -1e30f;
#pragma unroll
            for (int t = 0; t < 4; ++t)
#pragma unroll
                for (int r = 0; r < 4; ++r) {
                    const float lg = acc[t][r] + apv[t * 4 + r];
                    pv[t * 4 + r] = lg;
                    m = fmaxf(m, lg);
                }
            m = fmaxf(m, __shfl_xor(m, 16, 64));
            m = fmaxf(m, __shfl_xor(m, 32, 64));
            float ssum = 0.f;
#pragma unroll
            for (int j = 0; j < 16; ++j) { pv[j] = __expf(pv[j] - m); ssum += pv[j]; }
            ssum += __shfl_xor(ssum, 16, 64);
            ssum += __shfl_xor(ssum, 32, 64);
            const float rs = 1.f / ssum;
#pragma unroll
            for (int j = 0; j < 16; ++j) { pv[j] *= rs; S0loc[j] += pv[j]; }
#pragma unroll
            for (int t = 0; t < 4; ++t)
#pragma unroll
                for (int r = 0; r < 4; ++r)
                    Pt[16 * t + 4 * q + r][tok] = (half_t)pv[t * 4 + r];
        }
        __syncthreads();   // Xs/Qs/Pt all visible

        // ---------------- Phase B ----------------
        {
            const half_t* Bsrc = (sig == 0) ? &Xs[0][0] : &Qs[0][0];
            const int m   = lane & 31;
            const int h   = lane >> 5;
            const int d   = 32 * dh + m;
            const half_t* Arow0 = &Pt[m][0];
            const half_t* Arow1 = &Pt[32 + m][0];
#pragma unroll
            for (int st = 0; st < 4; ++st) {
                const int tB = 16 * st + 8 * h;
                const v8h a0 = *(const v8h*)(Arow0 + tB);
                const v8h a1 = *(const v8h*)(Arow1 + tB);
                v8h bf;
#pragma unroll
                for (int j = 0; j < 8; ++j)
                    bf[j] = Bsrc[(tB + j) * XSTR + d];
                accB[0] = __builtin_amdgcn_mfma_f32_32x32x16_f16(a0, bf, accB[0], 0, 0, 0);
                accB[1] = __builtin_amdgcn_mfma_f32_32x32x16_f16(a1, bf, accB[1], 0, 0, 0);
            }
        }
        __syncthreads();   // Phase B done -> LDS reusable next batch
    }

    // -------- flush --------
#pragma unroll
    for (int j = 0; j < 16; ++j) {
        float v = S0loc[j];
        v += __shfl_xor(v, 1, 64);
        v += __shfl_xor(v, 2, 64);
        v += __shfl_xor(v, 4, 64);
        v += __shfl_xor(v, 8, 64);
        S0loc[j] = v;
    }
    if (c0 == 0) {
#pragma unroll
        for (int t = 0; t < 4; ++t)
#pragma unroll
            for (int r = 0; r < 4; ++r)
                s0sh[wv][16 * t + 4 * q + r] = S0loc[t * 4 + r];
    }
    __syncthreads();

    if (mode == 1) {
        float* dstb = outbuf + (size_t)(n * CHUNKS + chunk) * STATS_PER_N;
        if (tid < 64)
            dstb[tid] = s0sh[0][tid] + s0sh[1][tid] + s0sh[2][tid] + s0sh[3][tid];
        const int d = 32 * dh + (lane & 31);
        float* dst = dstb + 64 + sig * 4096;
#pragma unroll
        for (int mt = 0; mt < 2; ++mt)
#pragma unroll
            for (int r = 0; r < 16; ++r) {
                const int kc = 32 * mt + (r & 3) + 8 * (r >> 2) + 4 * (lane >> 5);
                dst[kc * 64 + d] = accB[mt][r];
            }
    } else {
        float* sb = outbuf + (size_t)n * STATS_PER_N;
        if (tid < 64)
            atomicAdd(&sb[tid], s0sh[0][tid] + s0sh[1][tid] + s0sh[2][tid] + s0sh[3][tid]);
        const int d = 32 * dh + (lane & 31);
        float* dst = sb + 64 + sig * 4096;
#pragma unroll
        for (int mt = 0; mt < 2; ++mt)
#pragma unroll
            for (int r = 0; r < 16; ++r) {
                const int kc = 32 * mt + (r & 3) + 8 * (r >> 2) + 4 * (lane >> 5);
                atomicAdd(&dst[kc * 64 + d], accB[mt][r]);
            }
    }
}

// ---------------------------------------------------------------------------
// fin (grid 32): stats -> v0/v1/v2 transform + signed sqrt -> L2 normalize
// -> out. stats is 1 MB and L2-hot from main's atomics.
// ---------------------------------------------------------------------------
__global__ void fin_kernel(const float* __restrict__ w, const float* __restrict__ mu,
                           const float* __restrict__ cv, const float* __restrict__ stats,
                           float* __restrict__ out) {
    __shared__ float us[STATS_PER_N];
    __shared__ float red[4];
    const int n   = blockIdx.x;
    const int tid = threadIdx.x;
    const float* sb = stats + (size_t)n * STATS_PER_N;

    float ss = 0.f;
    if (tid < 64) {
        const float wv = w[tid];
        const float v = (sb[tid] - (float)T_ * wv) * rsqrtf(wv);
        const float u = (v >= 0.f) ? sqrtf(v) : -sqrtf(-v);
        us[tid * 129] = u;
        ss = fmaf(u, u, ss);
    }
#pragma unroll 1
    for (int i = 0; i < 16; ++i) {
        const int idx = i * 256 + tid;
        const int k = idx >> 6, d = idx & 63;
        const float v = (sb[64 + idx] - mu[idx] * sb[k]) * rsqrtf(w[k] * cv[idx]);
        const float u = (v >= 0.f) ? sqrtf(v) : -sqrtf(-v);
        us[k * 129 + 1 + d] = u;
        ss = fmaf(u, u, ss);
    }
#pragma unroll 1
    for (int i = 0; i < 16; ++i) {
        const int idx = i * 256 + tid;
        const int k = idx >> 6, d = idx & 63;
        const float m_ = mu[idx], c_ = cv[idx];
        const float s1v = sb[64 + idx], s2v = sb[64 + 4096 + idx];
        const float v = (s2v - 2.f * m_ * s1v + (m_ * m_ - c_) * sb[k]) *
                        (rsqrtf(2.f * w[k]) / c_);
        const float u = (v >= 0.f) ? sqrtf(v) : -sqrtf(-v);
        us[k * 129 + 65 + d] = u;
        ss = fmaf(u, u, ss);
    }
#pragma unroll
    for (int off = 32; off > 0; off >>= 1) ss += __shfl_xor(ss, off, 64);
    if ((tid & 63) == 0) red[tid >> 6] = ss;
    __syncthreads();
    const float tot = red[0] + red[1] + red[2] + red[3];
    const float rn = rsqrtf(tot);
    for (int e = tid; e < STATS_PER_N; e += 256)
        out[(size_t)n * STATS_PER_N + e] = us[e] * rn;
}

// ---------------------------------------------------------------------------
extern "C" void kernel_launch(void* const* d_in, const int* in_sizes, int n_in,
                              void* d_out, int out_size, void* d_ws, size_t ws_size,
                              hipStream_t stream) {
    const float* x  = (const float*)d_in[0];
    const float* w  = (const float*)d_in[1];
    const float* mu = (const float*)d_in[2];
    const float* cv = (const float*)d_in[3];
    float* out = (float*)d_out;

    // workspace: stats (264192 f) + Ap (64 f) + WH (8192 f16 = 4096 f)
    float* stats = (float*)d_ws;
    float* Ap    = stats + STATS_TOTAL;
    half_t* WH   = (half_t*)(Ap + K_);

    prep_kernel<<<42, 256, 0, stream>>>(w, mu, cv, Ap, WH, stats);
    main_kernel<<<dim3(CHUNKS, N_), 256, 0, stream>>>(x, Ap, WH, stats, 0);
    fin_kernel<<<N_, 256, 0, stream>>>(w, mu, cv, stats, out);
}

// Round 9
// 128.973 us; speedup vs baseline: 1.5838x; 1.2095x over previous
//
#include <hip/hip_runtime.h>
#include <math.h>

#define N_  32
#define T_  8192
#define D_  64
#define K_  64
#define CHUNKS 16                      // 512 blocks = exactly 2/CU, one round
#define TB 128                         // tokens per batch (R9: was 64)
#define NBATCH 4                       // 512 tokens per chunk / TB
#define STATS_PER_N (K_ + 2 * K_ * D_) // 8256
#define XSTR 72                        // f16 stride for Xs/Qs rows
#define PSTR 136                       // f16 stride for Pt rows (128 cols + 8 pad)

typedef _Float16 half_t;
typedef __attribute__((ext_vector_type(8)))  _Float16 v8h;
typedef __attribute__((ext_vector_type(4)))  float    v4f;
typedef __attribute__((ext_vector_type(16))) float    v16f;

// ---------------------------------------------------------------------------
// prep (grid 9): blocks 0..7 pack WH (f16 MFMA A-frag order);
// block 8: Ap[k] = 2 log w - 0.5*sum_d(log c + mu^2/c), and zero ssq[32].
// ---------------------------------------------------------------------------
__global__ void prep_kernel(const float* __restrict__ w, const float* __restrict__ mu,
                            const float* __restrict__ cv, float* __restrict__ Ap,
                            half_t* __restrict__ WH, float* __restrict__ ssq) {
    if (blockIdx.x < 8) {
#pragma unroll
        for (int i = 0; i < 4; ++i) {
            const int e = blockIdx.x * 1024 + i * 256 + threadIdx.x;  // 0..8191
            const int j = e & 7, l = (e >> 3) & 63, fs = e >> 9;
            const int tile = fs >> 2, s = fs & 3;
            const int kc = 16 * tile + (l & 15);
            const int f  = 32 * s + 8 * (l >> 4) + j;
            float val;
            if (f < 64) val = mu[kc * 64 + f] / cv[kc * 64 + f];
            else        val = -0.5f / cv[kc * 64 + (f - 64)];
            WH[e] = (half_t)val;
        }
    } else {
        if (threadIdx.x < 32) ssq[threadIdx.x] = 0.f;
        if (threadIdx.x < K_) {
            const int k = threadIdx.x;
            float acc = 0.f;
            for (int d = 0; d < D_; ++d) {
                const int idx = k * D_ + d;
                const float c = cv[idx], m = mu[idx];
                acc += logf(c) + m * m / c;
            }
            Ap[k] = 2.f * logf(w[k]) - 0.5f * acc;
        }
    }
}

// ---------------------------------------------------------------------------
// main: grid (16, 32) = 512 blocks, block 256 (4 waves), 2 blocks/CU.
// R9: HALVE THE PERIOD COUNT. Counter-consistent model of R3: each batch
// period is ~7080 cy with only ~1000 cy of issue — a ~5.5k-cy fixed
// latency/convoy cost per period, 16 periods/CU. Structural edits to the
// period (R5/R6/R7) all regressed; so instead run the SAME R3 pipeline at
// TB=128: 8 periods/CU of 2x work. Each wave processes two 16-token groups
// per batch (R3 code run twice); Phase B covers K=128 in 8 strips. At
// 2 blocks/CU the budget is 256 VGPR/wave (no spill) and 111 KB LDS.
// Uniform 4 batches/block — no ragged 5/6 chunks.
// ---------------------------------------------------------------------------
__launch_bounds__(256, 2)
__global__ void main_kernel(const float* __restrict__ x, const float* __restrict__ Ap,
                            const half_t* __restrict__ WH, float* __restrict__ outbuf,
                            int mode) {
    __shared__ half_t Xs[TB][XSTR];   // 18.4 KB
    __shared__ half_t Qs[TB][XSTR];   // 18.4 KB
    __shared__ half_t Pt[K_][PSTR];   // 17.4 KB (transposed p: row=kc, col=token)
    __shared__ float  s0sh[4][64];    // 1.0 KB

    const int tid  = threadIdx.x;
    const int lane = tid & 63;
    const int wv   = tid >> 6;
    const int chunk = blockIdx.x;
    const int n     = blockIdx.y;
    const int q     = lane >> 4;
    const int c0    = lane & 15;
    const int tok0  = 16 * wv + c0;        // group-0 token within the batch
    const int tok1  = tok0 + 64;           // group-1 token

    // resident weight A-frags
    v8h Wf[16];
#pragma unroll
    for (int t = 0; t < 4; ++t)
#pragma unroll
        for (int s = 0; s < 4; ++s)
            Wf[t * 4 + s] = *(const v8h*)(WH + (size_t)((t * 4 + s) * 64 + lane) * 8);

    float apv[16];
#pragma unroll
    for (int t = 0; t < 4; ++t)
#pragma unroll
        for (int r = 0; r < 4; ++r) apv[t * 4 + r] = Ap[16 * t + 4 * q + r];

    float S0loc[16];
#pragma unroll
    for (int j = 0; j < 16; ++j) S0loc[j] = 0.f;

    const int sig = wv >> 1;
    const int dh  = wv & 1;
    v16f accB[2];
#pragma unroll
    for (int m = 0; m < 2; ++m)
#pragma unroll
        for (int r = 0; r < 16; ++r) accB[m][r] = 0.f;

    const size_t xbase = ((size_t)n * T_ + (size_t)chunk * (NBATCH * TB)) * (size_t)D_;
    const float* xrow0 = x + xbase + tok0 * 64 + 8 * q;
    const float* xrow1 = x + xbase + tok1 * 64 + 8 * q;

    // preload batch 0 for both groups (8 float4 in flight)
    float4 RA[4], RB[4];
    RA[0] = *(const float4*)(xrow0);      RA[1] = *(const float4*)(xrow0 + 4);
    RA[2] = *(const float4*)(xrow0 + 32); RA[3] = *(const float4*)(xrow0 + 36);
    RB[0] = *(const float4*)(xrow1);      RB[1] = *(const float4*)(xrow1 + 4);
    RB[2] = *(const float4*)(xrow1 + 32); RB[3] = *(const float4*)(xrow1 + 36);

// one 16-token group: convert R -> frags, stage Xs/Qs, prefetch next batch,
// Phase-A MFMA + softmax, Pt write.  Verbatim R3 pipeline parameterized.
#define PROCESS_GROUP(Rg, xrowg, tokg)                                          \
    {                                                                           \
        v8h xh0, xh1, qh0, qh1;                                                 \
        {                                                                       \
            const float4 a = Rg[0], b = Rg[1], c = Rg[2], d = Rg[3];            \
            xh0[0] = (half_t)a.x; xh0[1] = (half_t)a.y; xh0[2] = (half_t)a.z; xh0[3] = (half_t)a.w; \
            xh0[4] = (half_t)b.x; xh0[5] = (half_t)b.y; xh0[6] = (half_t)b.z; xh0[7] = (half_t)b.w; \
            xh1[0] = (half_t)c.x; xh1[1] = (half_t)c.y; xh1[2] = (half_t)c.z; xh1[3] = (half_t)c.w; \
            xh1[4] = (half_t)d.x; xh1[5] = (half_t)d.y; xh1[6] = (half_t)d.z; xh1[7] = (half_t)d.w; \
            qh0[0] = (half_t)(a.x * a.x); qh0[1] = (half_t)(a.y * a.y);         \
            qh0[2] = (half_t)(a.z * a.z); qh0[3] = (half_t)(a.w * a.w);         \
            qh0[4] = (half_t)(b.x * b.x); qh0[5] = (half_t)(b.y * b.y);         \
            qh0[6] = (half_t)(b.z * b.z); qh0[7] = (half_t)(b.w * b.w);         \
            qh1[0] = (half_t)(c.x * c.x); qh1[1] = (half_t)(c.y * c.y);         \
            qh1[2] = (half_t)(c.z * c.z); qh1[3] = (half_t)(c.w * c.w);         \
            qh1[4] = (half_t)(d.x * d.x); qh1[5] = (half_t)(d.y * d.y);         \
            qh1[6] = (half_t)(d.z * d.z); qh1[7] = (half_t)(d.w * d.w);         \
            *(v8h*)&Xs[tokg][8 * q]      = xh0;                                 \
            *(v8h*)&Xs[tokg][32 + 8 * q] = xh1;                                 \
            *(v8h*)&Qs[tokg][8 * q]      = qh0;                                 \
            *(v8h*)&Qs[tokg][32 + 8 * q] = qh1;                                 \
        }                                                                       \
        if (batch + 1 < NBATCH) {                                               \
            const float* xr = xrowg + (size_t)(batch + 1) * TB * D_;            \
            Rg[0] = *(const float4*)(xr);                                       \
            Rg[1] = *(const float4*)(xr + 4);                                   \
            Rg[2] = *(const float4*)(xr + 32);                                  \
            Rg[3] = *(const float4*)(xr + 36);                                  \
        }                                                                       \
        {                                                                       \
            v4f acc[4];                                                         \
            _Pragma("unroll")                                                   \
            for (int t = 0; t < 4; ++t) acc[t] = (v4f)(0.f);                    \
            _Pragma("unroll")                                                   \
            for (int t = 0; t < 4; ++t) {                                       \
                acc[t] = __builtin_amdgcn_mfma_f32_16x16x32_f16(Wf[t * 4 + 0], xh0, acc[t], 0, 0, 0); \
                acc[t] = __builtin_amdgcn_mfma_f32_16x16x32_f16(Wf[t * 4 + 1], xh1, acc[t], 0, 0, 0); \
                acc[t] = __builtin_amdgcn_mfma_f32_16x16x32_f16(Wf[t * 4 + 2], qh0, acc[t], 0, 0, 0); \
                acc[t] = __builtin_amdgcn_mfma_f32_16x16x32_f16(Wf[t * 4 + 3], qh1, acc[t], 0, 0, 0); \
            }                                                                   \
            float pv[16];                                                       \
            float m = -1e30f;                                                   \
            _Pragma("unroll")                                                   \
            for (int t = 0; t < 4; ++t)                                         \
                _Pragma("unroll")                                               \
                for (int r = 0; r < 4; ++r) {                                   \
                    const float lg = acc[t][r] + apv[t * 4 + r];                \
                    pv[t * 4 + r] = lg;                                         \
                    m = fmaxf(m, lg);                                           \
                }                                                               \
            m = fmaxf(m, __shfl_xor(m, 16, 64));                                \
            m = fmaxf(m, __shfl_xor(m, 32, 64));                                \
            float ssum = 0.f;                                                   \
            _Pragma("unroll")                                                   \
            for (int j = 0; j < 16; ++j) { pv[j] = __expf(pv[j] - m); ssum += pv[j]; } \
            ssum += __shfl_xor(ssum, 16, 64);                                   \
            ssum += __shfl_xor(ssum, 32, 64);                                   \
            const float rs = 1.f / ssum;                                        \
            _Pragma("unroll")                                                   \
            for (int j = 0; j < 16; ++j) { pv[j] *= rs; S0loc[j] += pv[j]; }    \
            _Pragma("unroll")                                                   \
            for (int t = 0; t < 4; ++t)                                         \
                _Pragma("unroll")                                               \
                for (int r = 0; r < 4; ++r)                                     \
                    Pt[16 * t + 4 * q + r][tokg] = (half_t)pv[t * 4 + r];       \
        }                                                                       \
    }

#pragma unroll 1
    for (int batch = 0; batch < NBATCH; ++batch) {
        PROCESS_GROUP(RA, xrow0, tok0)
        PROCESS_GROUP(RB, xrow1, tok1)
        __syncthreads();   // Xs/Qs/Pt (128 tokens) all visible

        // ---------------- Phase B: K = 128 in 8 strips ----------------
        {
            const half_t* Bsrc = (sig == 0) ? &Xs[0][0] : &Qs[0][0];
            const int m   = lane & 31;
            const int h   = lane >> 5;
            const int d   = 32 * dh + m;
            const half_t* Arow0 = &Pt[m][0];
            const half_t* Arow1 = &Pt[32 + m][0];
#pragma unroll
            for (int st = 0; st < 8; ++st) {
                const int tB = 16 * st + 8 * h;
                const v8h a0 = *(const v8h*)(Arow0 + tB);
                const v8h a1 = *(const v8h*)(Arow1 + tB);
                v8h bf;
#pragma unroll
                for (int j = 0; j < 8; ++j)
                    bf[j] = Bsrc[(tB + j) * XSTR + d];
                accB[0] = __builtin_amdgcn_mfma_f32_32x32x16_f16(a0, bf, accB[0], 0, 0, 0);
                accB[1] = __builtin_amdgcn_mfma_f32_32x32x16_f16(a1, bf, accB[1], 0, 0, 0);
            }
        }
        __syncthreads();   // Phase B done -> LDS reusable next batch
    }
#undef PROCESS_GROUP

    // -------- flush --------
#pragma unroll
    for (int j = 0; j < 16; ++j) {
        float v = S0loc[j];
        v += __shfl_xor(v, 1, 64);
        v += __shfl_xor(v, 2, 64);
        v += __shfl_xor(v, 4, 64);
        v += __shfl_xor(v, 8, 64);
        S0loc[j] = v;
    }
    if (c0 == 0) {
#pragma unroll
        for (int t = 0; t < 4; ++t)
#pragma unroll
            for (int r = 0; r < 4; ++r)
                s0sh[wv][16 * t + 4 * q + r] = S0loc[t * 4 + r];
    }
    __syncthreads();

    if (mode == 1) {
        float* dstb = outbuf + (size_t)(n * CHUNKS + chunk) * STATS_PER_N;
        if (tid < 64)
            dstb[tid] = s0sh[0][tid] + s0sh[1][tid] + s0sh[2][tid] + s0sh[3][tid];
        const int d = 32 * dh + (lane & 31);
        float* dst = dstb + 64 + sig * 4096;
#pragma unroll
        for (int mt = 0; mt < 2; ++mt)
#pragma unroll
            for (int r = 0; r < 16; ++r) {
                const int kc = 32 * mt + (r & 3) + 8 * (r >> 2) + 4 * (lane >> 5);
                dst[kc * 64 + d] = accB[mt][r];
            }
    } else {
        float* sb = outbuf + (size_t)n * STATS_PER_N;
        if (tid < 64)
            atomicAdd(&sb[tid], s0sh[0][tid] + s0sh[1][tid] + s0sh[2][tid] + s0sh[3][tid]);
        const int d = 32 * dh + (lane & 31);
        float* dst = sb + 64 + sig * 4096;
#pragma unroll
        for (int mt = 0; mt < 2; ++mt)
#pragma unroll
            for (int r = 0; r < 16; ++r) {
                const int kc = 32 * mt + (r & 3) + 8 * (r >> 2) + 4 * (lane >> 5);
                atomicAdd(&dst[kc * 64 + d], accB[mt][r]);
            }
    }
}

// ---------------------------------------------------------------------------
// reduce_pow (grid (33, N)): sum partials over 16 chunks, apply v0/v1/v2
// transform + signed sqrt, write us in OUTPUT order; one ssq atomic per block.
// (R3 structure verbatim — measured best total.)
// ---------------------------------------------------------------------------
__global__ void reduce_pow_kernel(const float* __restrict__ partials,
                                  const float* __restrict__ w, const float* __restrict__ mu,
                                  const float* __restrict__ cv,
                                  float* __restrict__ us, float* __restrict__ ssq) {
    __shared__ float red[4];
    const int e = blockIdx.x * 256 + threadIdx.x;
    const int n = blockIdx.y;
    float u = 0.f;
    if (e < STATS_PER_N) {
        const float* base = partials + (size_t)n * CHUNKS * STATS_PER_N;
        float sv = 0.f;
#pragma unroll 8
        for (int c = 0; c < CHUNKS; ++c) sv += base[(size_t)c * STATS_PER_N + e];
        float v; int oidx;
        if (e < 64) {
            const float wv = w[e];
            v = (sv - (float)T_ * wv) * rsqrtf(wv);
            oidx = e * 129;
        } else if (e < 64 + 4096) {
            const int idx = e - 64, k = idx >> 6, d = idx & 63;
            float s0v = 0.f;
#pragma unroll 8
            for (int c = 0; c < CHUNKS; ++c) s0v += base[(size_t)c * STATS_PER_N + k];
            v = (sv - mu[idx] * s0v) * rsqrtf(w[k] * cv[idx]);
            oidx = k * 129 + 1 + d;
        } else {
            const int idx = e - 4160, k = idx >> 6, d = idx & 63;
            float s0v = 0.f, s1v = 0.f;
#pragma unroll 4
            for (int c = 0; c < CHUNKS; ++c) {
                s0v += base[(size_t)c * STATS_PER_N + k];
                s1v += base[(size_t)c * STATS_PER_N + 64 + idx];
            }
            const float m_ = mu[idx], c_ = cv[idx];
            v = (sv - 2.f * m_ * s1v + (m_ * m_ - c_) * s0v) * (rsqrtf(2.f * w[k]) / c_);
            oidx = k * 129 + 65 + d;
        }
        u = (v >= 0.f) ? sqrtf(v) : -sqrtf(-v);
        us[(size_t)n * STATS_PER_N + oidx] = u;
    }
    float ss = u * u;
#pragma unroll
    for (int off = 32; off > 0; off >>= 1) ss += __shfl_xor(ss, off, 64);
    if ((threadIdx.x & 63) == 0) red[threadIdx.x >> 6] = ss;
    __syncthreads();
    if (threadIdx.x == 0)
        atomicAdd(&ssq[n], red[0] + red[1] + red[2] + red[3]);
}

// ---------------------------------------------------------------------------
// scale (grid (33, N)): out = us * rsqrt(ssq[n])
// ---------------------------------------------------------------------------
__global__ void scale_kernel(const float* __restrict__ us, const float* __restrict__ ssq,
                             float* __restrict__ out) {
    const int e = blockIdx.x * 256 + threadIdx.x;
    const int n = blockIdx.y;
    if (e < STATS_PER_N)
        out[(size_t)n * STATS_PER_N + e] = us[(size_t)n * STATS_PER_N + e] * rsqrtf(ssq[n]);
}

// ---------------------------------------------------------------------------
// fallback finalize (small-ws atomic path).
// ---------------------------------------------------------------------------
__global__ void fin_kernel(const float* __restrict__ w, const float* __restrict__ mu,
                           const float* __restrict__ cv, const float* __restrict__ stats,
                           float* __restrict__ out) {
    __shared__ float us[STATS_PER_N];
    __shared__ float red[4];
    const int n   = blockIdx.x;
    const int tid = threadIdx.x;
    const float* sb = stats + (size_t)n * STATS_PER_N;

    float ss = 0.f;
    if (tid < 64) {
        const float wv = w[tid];
        const float v = (sb[tid] - (float)T_ * wv) * rsqrtf(wv);
        const float u = (v >= 0.f) ? sqrtf(v) : -sqrtf(-v);
        us[tid * 129] = u;
        ss = fmaf(u, u, ss);
    }
#pragma unroll 1
    for (int i = 0; i < 16; ++i) {
        const int idx = i * 256 + tid;
        const int k = idx >> 6, d = idx & 63;
        const float v = (sb[64 + idx] - mu[idx] * sb[k]) * rsqrtf(w[k] * cv[idx]);
        const float u = (v >= 0.f) ? sqrtf(v) : -sqrtf(-v);
        us[k * 129 + 1 + d] = u;
        ss = fmaf(u, u, ss);
    }
#pragma unroll 1
    for (int i = 0; i < 16; ++i) {
        const int idx = i * 256 + tid;
        const int k = idx >> 6, d = idx & 63;
        const float m_ = mu[idx], c_ = cv[idx];
        const float s1v = sb[64 + idx], s2v = sb[64 + 4096 + idx];
        const float v = (s2v - 2.f * m_ * s1v + (m_ * m_ - c_) * sb[k]) *
                        (rsqrtf(2.f * w[k]) / c_);
        const float u = (v >= 0.f) ? sqrtf(v) : -sqrtf(-v);
        us[k * 129 + 65 + d] = u;
        ss = fmaf(u, u, ss);
    }
#pragma unroll
    for (int off = 32; off > 0; off >>= 1) ss += __shfl_xor(ss, off, 64);
    if ((tid & 63) == 0) red[tid >> 6] = ss;
    __syncthreads();
    const float tot = red[0] + red[1] + red[2] + red[3];
    const float rn = rsqrtf(tot);
    for (int e = tid; e < STATS_PER_N; e += 256)
        out[(size_t)n * STATS_PER_N + e] = us[e] * rn;
}

// ---------------------------------------------------------------------------
extern "C" void kernel_launch(void* const* d_in, const int* in_sizes, int n_in,
                              void* d_out, int out_size, void* d_ws, size_t ws_size,
                              hipStream_t stream) {
    const float* x  = (const float*)d_in[0];
    const float* w  = (const float*)d_in[1];
    const float* mu = (const float*)d_in[2];
    const float* cv = (const float*)d_in[3];
    float* out = (float*)d_out;

    const size_t part_elems = (size_t)CHUNKS * N_ * STATS_PER_N;   // 4.23M floats
    const size_t us_elems   = (size_t)N_ * STATS_PER_N;
    const size_t need_big = (part_elems + us_elems + 32 + K_ + (size_t)K_ * 64) * sizeof(float);

    if (ws_size >= need_big) {
        float* partials = (float*)d_ws;
        float* us  = partials + part_elems;
        float* ssq = us + us_elems;
        float* Ap  = ssq + 32;
        half_t* WH = (half_t*)(Ap + K_);

        prep_kernel<<<9, 256, 0, stream>>>(w, mu, cv, Ap, WH, ssq);
        main_kernel<<<dim3(CHUNKS, N_), 256, 0, stream>>>(x, Ap, WH, partials, 1);
        reduce_pow_kernel<<<dim3(33, N_), 256, 0, stream>>>(partials, w, mu, cv, us, ssq);
        scale_kernel<<<dim3(33, N_), 256, 0, stream>>>(us, ssq, out);
    } else {
        float* stats = (float*)d_ws;
        float* ssq = stats + us_elems;
        float* Ap  = ssq + 32;
        half_t* WH = (half_t*)(Ap + K_);

        hipMemsetAsync(stats, 0, us_elems * sizeof(float), stream);
        prep_kernel<<<9, 256, 0, stream>>>(w, mu, cv, Ap, WH, ssq);
        main_kernel<<<dim3(CHUNKS, N_), 256, 0, stream>>>(x, Ap, WH, stats, 0);
        fin_kernel<<<N_, 256, 0, stream>>>(w, mu, cv, stats, out);
    }
}